// Round 8
// baseline (164.930 us; speedup 1.0000x reference)
//
#include <hip/hip_runtime.h>

// Problem constants (fixed by the dataset)
constexpr int S_  = 4096;
constexpr int B_  = 2;
constexpr int C_  = 256;
constexpr int H_  = 8;
constexpr int E_  = 131072;
constexpr int MR  = S_ * B_;   // 8192 rows for all GEMMs
constexpr int PREP_BLOCKS = 640;   // 512 hist + 128 W-cast

typedef __attribute__((ext_vector_type(8))) short bf16x8_t;
typedef __attribute__((ext_vector_type(4))) float f32x4_t;

__device__ __forceinline__ unsigned short f2bf(float f) {
    unsigned int u = __float_as_uint(f);
    u += 0x7fffu + ((u >> 16) & 1u);   // round-to-nearest-even
    return (unsigned short)(u >> 16);
}
__device__ __forceinline__ float bflo(unsigned int u) { return __uint_as_float(u << 16); }
__device__ __forceinline__ float bfhi(unsigned int u) { return __uint_as_float(u & 0xffff0000u); }

__device__ __forceinline__ void cast8(const float* __restrict__ src, unsigned short* __restrict__ dst, int i) {
    const float4* s = (const float4*)src + (size_t)i * 2;
    float4 a = s[0], b = s[1];
    uint4 o;
    o.x = (unsigned)f2bf(a.x) | ((unsigned)f2bf(a.y) << 16);
    o.y = (unsigned)f2bf(a.z) | ((unsigned)f2bf(a.w) << 16);
    o.z = (unsigned)f2bf(b.x) | ((unsigned)f2bf(b.y) << 16);
    o.w = (unsigned)f2bf(b.z) | ((unsigned)f2bf(b.w) << 16);
    *((uint4*)dst + i) = o;
}

// ---------------- K1: bucketed histogram + W casts; last block does the scan ----------------
// count/base/cursor have 2S entries: bucket A (k<2048) in [0,S), bucket B in [S,2S).

__global__ __launch_bounds__(256) void prep_kernel(
        const int* __restrict__ q_id, const int* __restrict__ k_id,
        const float* __restrict__ Wq, const float* __restrict__ Wk,
        const float* __restrict__ Wv, const float* __restrict__ Wx,
        unsigned short* __restrict__ Wb,
        int* __restrict__ count, int* done,
        int* __restrict__ base, int* __restrict__ cursor) {
    const int bid = blockIdx.x, tid = threadIdx.x;
    if (bid < 512) {
        int e = bid * 256 + tid;
        int q = q_id[e], k = k_id[e];
        atomicAdd(&count[q + ((k >> 11) << 12)], 1);   // bucket = (k>=2048)
    } else {
        int idx = bid - 512;
        int z = idx >> 5;
        const float* src = (z == 0) ? Wq : (z == 1) ? Wk : (z == 2) ? Wv : Wx;
        cast8(src, Wb + (size_t)z * (C_ * C_), (idx & 31) * 256 + tid);
    }

    // ---- last-arriving block performs the 8192-entry exclusive scan ----
    __shared__ int amLast;
    __syncthreads();   // vmcnt(0): my atomics/stores are complete before the done-add
    if (tid == 0) {
        int d = __hip_atomic_fetch_add(done, 1, __ATOMIC_RELAXED, __HIP_MEMORY_SCOPE_AGENT);
        amLast = (d == PREP_BLOCKS - 1);
    }
    __syncthreads();
    if (!amLast) return;
    __builtin_amdgcn_fence(__ATOMIC_ACQUIRE, "agent");   // invalidate caches before reading count

    const int lane = tid & 63, w = tid >> 6;
    const int4* cp = (const int4*)count;
    int4 c[8];
#pragma unroll
    for (int j = 0; j < 8; ++j) c[j] = cp[tid * 8 + j];
    int tsum = 0;
#pragma unroll
    for (int j = 0; j < 8; ++j) tsum += c[j].x + c[j].y + c[j].z + c[j].w;
    int incl = tsum;
#pragma unroll
    for (int off = 1; off < 64; off <<= 1) {
        int y = __shfl_up(incl, off);
        if (lane >= off) incl += y;
    }
    __shared__ int wsums[4];
    if (lane == 63) wsums[w] = incl;
    __syncthreads();
    int ws0 = wsums[0], ws1 = wsums[1], ws2 = wsums[2];
    if (tid == 0) base[2 * S_] = E_;
    int woff = (w > 0 ? ws0 : 0) + (w > 1 ? ws1 : 0) + (w > 2 ? ws2 : 0);
    int run = woff + incl - tsum;
    int idx = tid * 32;
#define EMIT(V) { base[idx] = run; cursor[idx] = run; run += (V); ++idx; }
#pragma unroll
    for (int j = 0; j < 8; ++j) {
        EMIT(c[j].x) EMIT(c[j].y) EMIT(c[j].z) EMIT(c[j].w)
    }
#undef EMIT
}

// ---------------- K2: scatter + QKV GEMM (A cast fp32->bf16 during staging) ----------------

__global__ __launch_bounds__(256) void scatter_qkv_kernel(
        const float* __restrict__ x,
        const int* __restrict__ q_id, const int* __restrict__ k_id,
        int* __restrict__ cursor, int* __restrict__ koff,
        const unsigned short* __restrict__ Wb,
        const float* __restrict__ bq, const float* __restrict__ bk, const float* __restrict__ bv,
        unsigned short* __restrict__ qb, unsigned short* __restrict__ kvb) {
    __shared__ __align__(16) unsigned short As[64][264];   // 33.8 KB, +8 pad
    const int bid = blockIdx.x, tid = threadIdx.x;
    if (bid >= 512) {
        int e = (bid - 512) * 256 + tid;
        int q = q_id[e], k = k_id[e];
        int pos = atomicAdd(&cursor[q + ((k >> 11) << 12)], 1);
        koff[pos] = k << 10;               // element offset of row-pair in kvb
        return;
    }
    const int nb = bid & 3, mg = bid >> 2;
    const int lane = tid & 63, wave = tid >> 6;
    const int l16 = lane & 15, quad = lane >> 4;
    const int colz = (nb << 6) + (wave << 4);

    // Three B-strips: rows [colz, colz+16) of Wq, Wk, Wv
    bf16x8_t breg[3][8];
#pragma unroll
    for (int z = 0; z < 3; ++z) {
        const unsigned short* Wrow = Wb + (size_t)z * (C_ * C_) + (size_t)(colz + l16) * C_;
#pragma unroll
        for (int ks = 0; ks < 8; ++ks)
            breg[z][ks] = *(const bf16x8_t*)(Wrow + ks * 32 + quad * 8);
    }
    const float bc0 = bq[colz + l16];
    const float bc1 = bk[colz + l16];
    const float bc2 = bv[colz + l16];

    const int mbase = mg * 64;
    // stage A: 64 rows x 256 cols, fp32 -> bf16 into LDS
#pragma unroll
    for (int it = 0; it < 8; ++it) {
        int u = it * 256 + tid;
        int r = u >> 5, cc = (u & 31) << 3;
        const float4* s = (const float4*)(x + (size_t)(mbase + r) * C_ + cc);
        float4 a = s[0], b = s[1];
        uint4 o;
        o.x = (unsigned)f2bf(a.x) | ((unsigned)f2bf(a.y) << 16);
        o.y = (unsigned)f2bf(a.z) | ((unsigned)f2bf(a.w) << 16);
        o.z = (unsigned)f2bf(b.x) | ((unsigned)f2bf(b.y) << 16);
        o.w = (unsigned)f2bf(b.z) | ((unsigned)f2bf(b.w) << 16);
        *(uint4*)&As[r][cc] = o;
    }
    __syncthreads();

#pragma unroll
    for (int mt = 0; mt < 4; ++mt) {
        bf16x8_t a[8];
#pragma unroll
        for (int ks = 0; ks < 8; ++ks)
            a[ks] = *(const bf16x8_t*)&As[mt * 16 + l16][ks * 32 + quad * 8];
        const int row0 = mbase + mt * 16 + quad * 4;
        {   // q
            f32x4_t acc = {0.f, 0.f, 0.f, 0.f};
#pragma unroll
            for (int ks = 0; ks < 8; ++ks)
                acc = __builtin_amdgcn_mfma_f32_16x16x32_bf16(a[ks], breg[0][ks], acc, 0, 0, 0);
#pragma unroll
            for (int r = 0; r < 4; ++r)
                qb[(size_t)(row0 + r) * 256 + colz + l16] = f2bf(acc[r] + bc0);
        }
        {   // k  (kvb cols [0,256))
            f32x4_t acc = {0.f, 0.f, 0.f, 0.f};
#pragma unroll
            for (int ks = 0; ks < 8; ++ks)
                acc = __builtin_amdgcn_mfma_f32_16x16x32_bf16(a[ks], breg[1][ks], acc, 0, 0, 0);
#pragma unroll
            for (int r = 0; r < 4; ++r)
                kvb[(size_t)(row0 + r) * 512 + colz + l16] = f2bf(acc[r] + bc1);
        }
        {   // v  (kvb cols [256,512))
            f32x4_t acc = {0.f, 0.f, 0.f, 0.f};
#pragma unroll
            for (int ks = 0; ks < 8; ++ks)
                acc = __builtin_amdgcn_mfma_f32_16x16x32_bf16(a[ks], breg[2][ks], acc, 0, 0, 0);
#pragma unroll
            for (int r = 0; r < 4; ++r)
                kvb[(size_t)(row0 + r) * 512 + 256 + colz + l16] = f2bf(acc[r] + bc2);
        }
    }
}

// ---------------- K3: edge attention, 2-bucket, 8-deep gather pipeline ----------------

__global__ __launch_bounds__(256) void attn_edge(
        const unsigned short* __restrict__ qb, const unsigned short* __restrict__ kvb,
        const int* __restrict__ base, const int* __restrict__ koff,
        unsigned short* __restrict__ attnb) {
    __shared__ float red[2][64][9];
    const int lane = threadIdx.x & 63;
    const int wave = threadIdx.x >> 6;
    const int rw = wave >> 1, part = wave & 1;
    const int s = blockIdx.x * 2 + rw;
    const int half = lane >> 5, hl = lane & 31;

    const uint4 qq = *((const uint4*)(qb + (size_t)(s * 2 + half) * C_) + hl);
    const float q0 = bflo(qq.x), q1 = bfhi(qq.x), q2 = bflo(qq.y), q3 = bfhi(qq.y);
    const float q4 = bflo(qq.z), q5 = bfhi(qq.z), q6 = bflo(qq.w), q7 = bfhi(qq.w);

    float a0 = 0.f, a1 = 0.f, a2 = 0.f, a3 = 0.f, a4 = 0.f, a5 = 0.f, a6 = 0.f, a7 = 0.f;
    float wsum = 0.f;
    const float scale = 0.17677669529663687f;   // 1/sqrt(32)

    auto edge = [&](const uint4& kk, const uint4& vv) {
        float p = q0 * bflo(kk.x) + q1 * bfhi(kk.x)
                + q2 * bflo(kk.y) + q3 * bfhi(kk.y)
                + q4 * bflo(kk.z) + q5 * bfhi(kk.z)
                + q6 * bflo(kk.w) + q7 * bfhi(kk.w);
        p += __shfl_xor(p, 1);
        p += __shfl_xor(p, 2);
        const float w = __expf(p * scale);
        a0 = fmaf(w, bflo(vv.x), a0); a1 = fmaf(w, bfhi(vv.x), a1);
        a2 = fmaf(w, bflo(vv.y), a2); a3 = fmaf(w, bfhi(vv.y), a3);
        a4 = fmaf(w, bflo(vv.z), a4); a5 = fmaf(w, bfhi(vv.z), a5);
        a6 = fmaf(w, bflo(vv.w), a6); a7 = fmaf(w, bfhi(vv.w), a7);
        wsum += w;
    };
    auto fetch = [&](int my, int t, uint4& kk, uint4& vv) {
        int o = __builtin_amdgcn_readlane(my, part + 2 * t);
        const uint4* p = (const uint4*)(kvb + o + half * 512);
        kk = p[hl]; vv = p[32 + hl];
    };

    // two k-buckets; each has a ~4 MB kvb working set (XCD L2-resident).
#pragma unroll
    for (int seg = 0; seg < 2; ++seg) {
        const int cb = seg * S_ + s;
        const int e0 = __builtin_amdgcn_readfirstlane(base[cb]);
        const int e1 = __builtin_amdgcn_readfirstlane(base[cb + 1]);
        for (int b0 = e0; b0 < e1; b0 += 64) {
            const int m = min(64, e1 - b0);
            const int my = koff[b0 + ((lane < m) ? lane : 0)];
            const int nm = (m > part) ? ((m - part + 1) >> 1) : 0;
            uint4 k0 = {}, v0 = {}, k1 = {}, v1 = {};
            uint4 k2 = {}, v2 = {}, k3 = {}, v3 = {};
            uint4 k4 = {}, v4 = {}, k5 = {}, v5 = {};
            uint4 k6 = {}, v6 = {}, k7 = {}, v7 = {};
            if (nm > 0) fetch(my, 0, k0, v0);
            if (nm > 1) fetch(my, 1, k1, v1);
            if (nm > 2) fetch(my, 2, k2, v2);
            if (nm > 3) fetch(my, 3, k3, v3);
            if (nm > 4) fetch(my, 4, k4, v4);
            if (nm > 5) fetch(my, 5, k5, v5);
            if (nm > 6) fetch(my, 6, k6, v6);
            if (nm > 7) fetch(my, 7, k7, v7);
            int t = 0;
            for (; t + 15 < nm; t += 8) {
                edge(k0, v0); fetch(my, t + 8,  k0, v0);
                edge(k1, v1); fetch(my, t + 9,  k1, v1);
                edge(k2, v2); fetch(my, t + 10, k2, v2);
                edge(k3, v3); fetch(my, t + 11, k3, v3);
                edge(k4, v4); fetch(my, t + 12, k4, v4);
                edge(k5, v5); fetch(my, t + 13, k5, v5);
                edge(k6, v6); fetch(my, t + 14, k6, v6);
                edge(k7, v7); fetch(my, t + 15, k7, v7);
            }
            const int rem = nm - t;   // 0..15
            if (rem > 0)  { edge(k0, v0); if (rem > 8)  fetch(my, t + 8,  k0, v0); }
            if (rem > 1)  { edge(k1, v1); if (rem > 9)  fetch(my, t + 9,  k1, v1); }
            if (rem > 2)  { edge(k2, v2); if (rem > 10) fetch(my, t + 10, k2, v2); }
            if (rem > 3)  { edge(k3, v3); if (rem > 11) fetch(my, t + 11, k3, v3); }
            if (rem > 4)  { edge(k4, v4); if (rem > 12) fetch(my, t + 12, k4, v4); }
            if (rem > 5)  { edge(k5, v5); if (rem > 13) fetch(my, t + 13, k5, v5); }
            if (rem > 6)  { edge(k6, v6); if (rem > 14) fetch(my, t + 14, k6, v6); }
            if (rem > 7)  edge(k7, v7);
            if (rem > 8)  edge(k0, v0);
            if (rem > 9)  edge(k1, v1);
            if (rem > 10) edge(k2, v2);
            if (rem > 11) edge(k3, v3);
            if (rem > 12) edge(k4, v4);
            if (rem > 13) edge(k5, v5);
            if (rem > 14) edge(k6, v6);
        }
    }

    if (part == 1) {
        float* r = red[rw][lane];
        r[0] = a0; r[1] = a1; r[2] = a2; r[3] = a3;
        r[4] = a4; r[5] = a5; r[6] = a6; r[7] = a7; r[8] = wsum;
    }
    __syncthreads();
    if (part == 0) {
        const float* r = red[rw][lane];
        a0 += r[0]; a1 += r[1]; a2 += r[2]; a3 += r[3];
        a4 += r[4]; a5 += r[5]; a6 += r[6]; a7 += r[7]; wsum += r[8];
        const float inv = 1.0f / wsum;
        uint4 o;
        o.x = (unsigned)f2bf(a0 * inv) | ((unsigned)f2bf(a1 * inv) << 16);
        o.y = (unsigned)f2bf(a2 * inv) | ((unsigned)f2bf(a3 * inv) << 16);
        o.z = (unsigned)f2bf(a4 * inv) | ((unsigned)f2bf(a5 * inv) << 16);
        o.w = (unsigned)f2bf(a6 * inv) | ((unsigned)f2bf(a7 * inv) << 16);
        *((uint4*)(attnb + (size_t)(s * 2 + half) * C_) + hl) = o;
    }
}

// ---------------- K4: output projection (weights-in-registers) ----------------

__global__ __launch_bounds__(256) void gemm_proj(
        const unsigned short* __restrict__ attnb, const unsigned short* __restrict__ Wxb,
        const float* __restrict__ bx, float* __restrict__ out) {
    __shared__ __align__(16) unsigned short As[64][264];
    const int tid = threadIdx.x;
    const int nb = blockIdx.x & 3, mg = blockIdx.x >> 2;
    const int lane = tid & 63, wave = tid >> 6;
    const int l16 = lane & 15, quad = lane >> 4;
    const int colz = (nb << 6) + (wave << 4);

    const unsigned short* Wrow = Wxb + (size_t)(colz + l16) * C_;
    bf16x8_t breg[8];
#pragma unroll
    for (int ks = 0; ks < 8; ++ks)
        breg[ks] = *(const bf16x8_t*)(Wrow + ks * 32 + quad * 8);
    const float bcol = bx[colz + l16];

    const int mbase = mg * 64;
#pragma unroll
    for (int it = 0; it < 8; ++it) {
        int l = it * 256 + tid;
        int r = l >> 5, cc = (l & 31) << 3;
        *(uint4*)&As[r][cc] = *(const uint4*)&attnb[(size_t)(mbase + r) * C_ + cc];
    }
    __syncthreads();
#pragma unroll
    for (int mt = 0; mt < 4; ++mt) {
        f32x4_t acc = {0.f, 0.f, 0.f, 0.f};
#pragma unroll
        for (int ks = 0; ks < 8; ++ks) {
            bf16x8_t a = *(const bf16x8_t*)&As[mt * 16 + l16][ks * 32 + quad * 8];
            acc = __builtin_amdgcn_mfma_f32_16x16x32_bf16(a, breg[ks], acc, 0, 0, 0);
        }
        const int row0 = mbase + mt * 16 + quad * 4;
#pragma unroll
        for (int r = 0; r < 4; ++r)
            out[(size_t)(row0 + r) * C_ + colz + l16] = acc[r] + bcol;
    }
}

// ---------------- launch ----------------

extern "C" void kernel_launch(void* const* d_in, const int* in_sizes, int n_in,
                              void* d_out, int out_size, void* d_ws, size_t ws_size,
                              hipStream_t stream) {
    const float* x  = (const float*)d_in[0];
    const int* q_id = (const int*)d_in[1];
    const int* k_id = (const int*)d_in[2];
    const float* Wq = (const float*)d_in[3];
    const float* bq = (const float*)d_in[4];
    const float* Wk = (const float*)d_in[5];
    const float* bk = (const float*)d_in[6];
    const float* Wv = (const float*)d_in[7];
    const float* bv = (const float*)d_in[8];
    const float* Wx = (const float*)d_in[9];
    const float* bx = (const float*)d_in[10];
    float* out = (float*)d_out;

    char* ws = (char*)d_ws;
    unsigned short* qb    = (unsigned short*)ws;   ws += (size_t)MR * C_ * 2;
    unsigned short* kvb   = (unsigned short*)ws;   ws += (size_t)MR * 512 * 2;
    unsigned short* attnb = (unsigned short*)ws;   ws += (size_t)MR * C_ * 2;
    unsigned short* Wb    = (unsigned short*)ws;   ws += (size_t)4 * C_ * C_ * 2;
    int* count = (int*)ws;                         ws += 2 * S_ * 4;
    int* done  = (int*)ws;                         ws += 16 * 4;
    int* base  = (int*)ws;                         ws += (2 * S_ + 1) * 4;
    int* cursor = (int*)ws;                        ws += 2 * S_ * 4;
    int* koff_sorted = (int*)ws;

    hipMemsetAsync(count, 0, (2 * S_ + 16) * sizeof(int), stream);   // count + done
    prep_kernel<<<PREP_BLOCKS, 256, 0, stream>>>(q_id, k_id, Wq, Wk, Wv, Wx, Wb,
                                                 count, done, base, cursor);
    scatter_qkv_kernel<<<1024, 256, 0, stream>>>(x, q_id, k_id, cursor, koff_sorted,
                                                 Wb, bq, bk, bv, qb, kvb);
    attn_edge<<<S_ / 2, 256, 0, stream>>>(qb, kvb, base, koff_sorted, attnb);
    gemm_proj<<<512, 256, 0, stream>>>(attnb, Wb + (size_t)3 * C_ * C_, bx, out);
}

// Round 9
// 147.517 us; speedup vs baseline: 1.1180x; 1.1180x over previous
//
#include <hip/hip_runtime.h>

// Problem constants (fixed by the dataset)
constexpr int S_  = 4096;
constexpr int B_  = 2;
constexpr int C_  = 256;
constexpr int H_  = 8;
constexpr int E_  = 131072;
constexpr int MR  = S_ * B_;   // 8192 rows for all GEMMs
constexpr int PREP_BLOCKS = 512;   // hist only; last block scans

typedef __attribute__((ext_vector_type(8))) short bf16x8_t;
typedef __attribute__((ext_vector_type(4))) float f32x4_t;

__device__ __forceinline__ unsigned short f2bf(float f) {
    unsigned int u = __float_as_uint(f);
    u += 0x7fffu + ((u >> 16) & 1u);   // round-to-nearest-even
    return (unsigned short)(u >> 16);
}
__device__ __forceinline__ float bflo(unsigned int u) { return __uint_as_float(u << 16); }
__device__ __forceinline__ float bfhi(unsigned int u) { return __uint_as_float(u & 0xffff0000u); }

// load 8 fp32 -> bf16x8 register fragment (for weights-in-registers B-strips)
__device__ __forceinline__ bf16x8_t loadW8(const float* __restrict__ p) {
    float4 a = *(const float4*)p, b = *(const float4*)(p + 4);
    union { uint4 u; bf16x8_t v; } r;
    r.u.x = (unsigned)f2bf(a.x) | ((unsigned)f2bf(a.y) << 16);
    r.u.y = (unsigned)f2bf(a.z) | ((unsigned)f2bf(a.w) << 16);
    r.u.z = (unsigned)f2bf(b.x) | ((unsigned)f2bf(b.y) << 16);
    r.u.w = (unsigned)f2bf(b.z) | ((unsigned)f2bf(b.w) << 16);
    return r.v;
}

// ---------------- K1: bucketed histogram; last block does the scan ----------------
// count/base/cursor have 2S entries: bucket A (k<2048) in [0,S), bucket B in [S,2S).

__global__ __launch_bounds__(256) void prep_kernel(
        const int* __restrict__ q_id, const int* __restrict__ k_id,
        int* __restrict__ count, int* done,
        int* __restrict__ base, int* __restrict__ cursor) {
    const int bid = blockIdx.x, tid = threadIdx.x;
    {
        int e = bid * 256 + tid;
        int q = q_id[e], k = k_id[e];
        atomicAdd(&count[q + ((k >> 11) << 12)], 1);   // bucket = (k>=2048)
    }

    // ---- last-arriving block performs the 8192-entry exclusive scan ----
    __shared__ int amLast;
    __syncthreads();   // my atomics are issued before the done-add
    if (tid == 0) {
        int d = __hip_atomic_fetch_add(done, 1, __ATOMIC_RELAXED, __HIP_MEMORY_SCOPE_AGENT);
        amLast = (d == PREP_BLOCKS - 1);
    }
    __syncthreads();
    if (!amLast) return;
    __builtin_amdgcn_fence(__ATOMIC_ACQUIRE, "agent");   // invalidate caches before reading count

    const int lane = tid & 63, w = tid >> 6;
    const int4* cp = (const int4*)count;
    int4 c[8];
#pragma unroll
    for (int j = 0; j < 8; ++j) c[j] = cp[tid * 8 + j];
    int tsum = 0;
#pragma unroll
    for (int j = 0; j < 8; ++j) tsum += c[j].x + c[j].y + c[j].z + c[j].w;
    int incl = tsum;
#pragma unroll
    for (int off = 1; off < 64; off <<= 1) {
        int y = __shfl_up(incl, off);
        if (lane >= off) incl += y;
    }
    __shared__ int wsums[4];
    if (lane == 63) wsums[w] = incl;
    __syncthreads();
    int ws0 = wsums[0], ws1 = wsums[1], ws2 = wsums[2];
    if (tid == 0) base[2 * S_] = E_;
    int woff = (w > 0 ? ws0 : 0) + (w > 1 ? ws1 : 0) + (w > 2 ? ws2 : 0);
    int run = woff + incl - tsum;
    int idx = tid * 32;
#define EMIT(V) { base[idx] = run; cursor[idx] = run; run += (V); ++idx; }
#pragma unroll
    for (int j = 0; j < 8; ++j) {
        EMIT(c[j].x) EMIT(c[j].y) EMIT(c[j].z) EMIT(c[j].w)
    }
#undef EMIT
}

// ---------------- K2: scatter + QKV GEMM (fp32 W loaded+cast directly to registers) ----------------

__global__ __launch_bounds__(256) void scatter_qkv_kernel(
        const float* __restrict__ x,
        const int* __restrict__ q_id, const int* __restrict__ k_id,
        int* __restrict__ cursor, int* __restrict__ koff,
        const float* __restrict__ Wq, const float* __restrict__ Wk, const float* __restrict__ Wv,
        const float* __restrict__ bq, const float* __restrict__ bk, const float* __restrict__ bv,
        unsigned short* __restrict__ qb, unsigned short* __restrict__ kvb) {
    __shared__ __align__(16) unsigned short As[64][264];   // 33.8 KB, +8 pad
    const int bid = blockIdx.x, tid = threadIdx.x;
    if (bid >= 512) {
        int e = (bid - 512) * 256 + tid;
        int q = q_id[e], k = k_id[e];
        int pos = atomicAdd(&cursor[q + ((k >> 11) << 12)], 1);
        koff[pos] = k << 10;               // element offset of row-pair in kvb
        return;
    }
    const int nb = bid & 3, mg = bid >> 2;
    const int lane = tid & 63, wave = tid >> 6;
    const int l16 = lane & 15, quad = lane >> 4;
    const int colz = (nb << 6) + (wave << 4);

    // Three B-strips: rows [colz, colz+16) of Wq, Wk, Wv — loaded fp32, cast to bf16 regs
    const float* Ws0 = Wq + (size_t)(colz + l16) * C_ + quad * 8;
    const float* Ws1 = Wk + (size_t)(colz + l16) * C_ + quad * 8;
    const float* Ws2 = Wv + (size_t)(colz + l16) * C_ + quad * 8;
    bf16x8_t breg[3][8];
#pragma unroll
    for (int ks = 0; ks < 8; ++ks) {
        breg[0][ks] = loadW8(Ws0 + ks * 32);
        breg[1][ks] = loadW8(Ws1 + ks * 32);
        breg[2][ks] = loadW8(Ws2 + ks * 32);
    }
    const float bc0 = bq[colz + l16];
    const float bc1 = bk[colz + l16];
    const float bc2 = bv[colz + l16];

    const int mbase = mg * 64;
    // stage A: 64 rows x 256 cols, fp32 -> bf16 into LDS
#pragma unroll
    for (int it = 0; it < 8; ++it) {
        int u = it * 256 + tid;
        int r = u >> 5, cc = (u & 31) << 3;
        const float4* s = (const float4*)(x + (size_t)(mbase + r) * C_ + cc);
        float4 a = s[0], b = s[1];
        uint4 o;
        o.x = (unsigned)f2bf(a.x) | ((unsigned)f2bf(a.y) << 16);
        o.y = (unsigned)f2bf(a.z) | ((unsigned)f2bf(a.w) << 16);
        o.z = (unsigned)f2bf(b.x) | ((unsigned)f2bf(b.y) << 16);
        o.w = (unsigned)f2bf(b.z) | ((unsigned)f2bf(b.w) << 16);
        *(uint4*)&As[r][cc] = o;
    }
    __syncthreads();

#pragma unroll
    for (int mt = 0; mt < 4; ++mt) {
        bf16x8_t a[8];
#pragma unroll
        for (int ks = 0; ks < 8; ++ks)
            a[ks] = *(const bf16x8_t*)&As[mt * 16 + l16][ks * 32 + quad * 8];
        const int row0 = mbase + mt * 16 + quad * 4;
        {   // q
            f32x4_t acc = {0.f, 0.f, 0.f, 0.f};
#pragma unroll
            for (int ks = 0; ks < 8; ++ks)
                acc = __builtin_amdgcn_mfma_f32_16x16x32_bf16(a[ks], breg[0][ks], acc, 0, 0, 0);
#pragma unroll
            for (int r = 0; r < 4; ++r)
                qb[(size_t)(row0 + r) * 256 + colz + l16] = f2bf(acc[r] + bc0);
        }
        {   // k  (kvb cols [0,256))
            f32x4_t acc = {0.f, 0.f, 0.f, 0.f};
#pragma unroll
            for (int ks = 0; ks < 8; ++ks)
                acc = __builtin_amdgcn_mfma_f32_16x16x32_bf16(a[ks], breg[1][ks], acc, 0, 0, 0);
#pragma unroll
            for (int r = 0; r < 4; ++r)
                kvb[(size_t)(row0 + r) * 512 + colz + l16] = f2bf(acc[r] + bc1);
        }
        {   // v  (kvb cols [256,512))
            f32x4_t acc = {0.f, 0.f, 0.f, 0.f};
#pragma unroll
            for (int ks = 0; ks < 8; ++ks)
                acc = __builtin_amdgcn_mfma_f32_16x16x32_bf16(a[ks], breg[2][ks], acc, 0, 0, 0);
#pragma unroll
            for (int r = 0; r < 4; ++r)
                kvb[(size_t)(row0 + r) * 512 + 256 + colz + l16] = f2bf(acc[r] + bc2);
        }
    }
}

// ---------------- K3: edge attention, 2-bucket, 4-deep gather pipeline (R5 proven) ----------------

__global__ __launch_bounds__(256) void attn_edge(
        const unsigned short* __restrict__ qb, const unsigned short* __restrict__ kvb,
        const int* __restrict__ base, const int* __restrict__ koff,
        unsigned short* __restrict__ attnb) {
    __shared__ float red[2][64][9];
    const int lane = threadIdx.x & 63;
    const int wave = threadIdx.x >> 6;
    const int rw = wave >> 1, part = wave & 1;
    const int s = blockIdx.x * 2 + rw;
    const int half = lane >> 5, hl = lane & 31;

    const uint4 qq = *((const uint4*)(qb + (size_t)(s * 2 + half) * C_) + hl);
    const float q0 = bflo(qq.x), q1 = bfhi(qq.x), q2 = bflo(qq.y), q3 = bfhi(qq.y);
    const float q4 = bflo(qq.z), q5 = bfhi(qq.z), q6 = bflo(qq.w), q7 = bfhi(qq.w);

    float a0 = 0.f, a1 = 0.f, a2 = 0.f, a3 = 0.f, a4 = 0.f, a5 = 0.f, a6 = 0.f, a7 = 0.f;
    float wsum = 0.f;
    const float scale = 0.17677669529663687f;   // 1/sqrt(32)

    auto edge = [&](const uint4& kk, const uint4& vv) {
        float p = q0 * bflo(kk.x) + q1 * bfhi(kk.x)
                + q2 * bflo(kk.y) + q3 * bfhi(kk.y)
                + q4 * bflo(kk.z) + q5 * bfhi(kk.z)
                + q6 * bflo(kk.w) + q7 * bfhi(kk.w);
        p += __shfl_xor(p, 1);
        p += __shfl_xor(p, 2);
        const float w = __expf(p * scale);
        a0 = fmaf(w, bflo(vv.x), a0); a1 = fmaf(w, bfhi(vv.x), a1);
        a2 = fmaf(w, bflo(vv.y), a2); a3 = fmaf(w, bfhi(vv.y), a3);
        a4 = fmaf(w, bflo(vv.z), a4); a5 = fmaf(w, bfhi(vv.z), a5);
        a6 = fmaf(w, bflo(vv.w), a6); a7 = fmaf(w, bfhi(vv.w), a7);
        wsum += w;
    };
    auto fetch = [&](int my, int t, uint4& kk, uint4& vv) {
        int o = __builtin_amdgcn_readlane(my, part + 2 * t);
        const uint4* p = (const uint4*)(kvb + o + half * 512);
        kk = p[hl]; vv = p[32 + hl];
    };

    // two k-buckets; each has a ~4 MB kvb working set (XCD L2-resident).
#pragma unroll
    for (int seg = 0; seg < 2; ++seg) {
        const int cb = seg * S_ + s;
        const int e0 = __builtin_amdgcn_readfirstlane(base[cb]);
        const int e1 = __builtin_amdgcn_readfirstlane(base[cb + 1]);
        for (int b0 = e0; b0 < e1; b0 += 64) {
            const int m = min(64, e1 - b0);
            const int my = koff[b0 + ((lane < m) ? lane : 0)];
            const int nm = (m > part) ? ((m - part + 1) >> 1) : 0;
            uint4 k0 = {}, v0 = {}, k1 = {}, v1 = {};
            uint4 k2 = {}, v2 = {}, k3 = {}, v3 = {};
            if (nm > 0) fetch(my, 0, k0, v0);
            if (nm > 1) fetch(my, 1, k1, v1);
            if (nm > 2) fetch(my, 2, k2, v2);
            if (nm > 3) fetch(my, 3, k3, v3);
            int t = 0;
            for (; t + 7 < nm; t += 4) {
                edge(k0, v0); fetch(my, t + 4, k0, v0);
                edge(k1, v1); fetch(my, t + 5, k1, v1);
                edge(k2, v2); fetch(my, t + 6, k2, v2);
                edge(k3, v3); fetch(my, t + 7, k3, v3);
            }
            const int rem = nm - t;   // 0..7
            if (rem > 0) { edge(k0, v0); if (rem > 4) fetch(my, t + 4, k0, v0); }
            if (rem > 1) { edge(k1, v1); if (rem > 5) fetch(my, t + 5, k1, v1); }
            if (rem > 2) { edge(k2, v2); if (rem > 6) fetch(my, t + 6, k2, v2); }
            if (rem > 3) edge(k3, v3);
            if (rem > 4) edge(k0, v0);
            if (rem > 5) edge(k1, v1);
            if (rem > 6) edge(k2, v2);
        }
    }

    if (part == 1) {
        float* r = red[rw][lane];
        r[0] = a0; r[1] = a1; r[2] = a2; r[3] = a3;
        r[4] = a4; r[5] = a5; r[6] = a6; r[7] = a7; r[8] = wsum;
    }
    __syncthreads();
    if (part == 0) {
        const float* r = red[rw][lane];
        a0 += r[0]; a1 += r[1]; a2 += r[2]; a3 += r[3];
        a4 += r[4]; a5 += r[5]; a6 += r[6]; a7 += r[7]; wsum += r[8];
        const float inv = 1.0f / wsum;
        uint4 o;
        o.x = (unsigned)f2bf(a0 * inv) | ((unsigned)f2bf(a1 * inv) << 16);
        o.y = (unsigned)f2bf(a2 * inv) | ((unsigned)f2bf(a3 * inv) << 16);
        o.z = (unsigned)f2bf(a4 * inv) | ((unsigned)f2bf(a5 * inv) << 16);
        o.w = (unsigned)f2bf(a6 * inv) | ((unsigned)f2bf(a7 * inv) << 16);
        *((uint4*)(attnb + (size_t)(s * 2 + half) * C_) + hl) = o;
    }
}

// ---------------- K4: output projection (fp32 Wx loaded+cast directly) ----------------

__global__ __launch_bounds__(256) void gemm_proj(
        const unsigned short* __restrict__ attnb, const float* __restrict__ Wx,
        const float* __restrict__ bx, float* __restrict__ out) {
    __shared__ __align__(16) unsigned short As[64][264];
    const int tid = threadIdx.x;
    const int nb = blockIdx.x & 3, mg = blockIdx.x >> 2;
    const int lane = tid & 63, wave = tid >> 6;
    const int l16 = lane & 15, quad = lane >> 4;
    const int colz = (nb << 6) + (wave << 4);

    const float* Wrow = Wx + (size_t)(colz + l16) * C_ + quad * 8;
    bf16x8_t breg[8];
#pragma unroll
    for (int ks = 0; ks < 8; ++ks)
        breg[ks] = loadW8(Wrow + ks * 32);
    const float bcol = bx[colz + l16];

    const int mbase = mg * 64;
#pragma unroll
    for (int it = 0; it < 8; ++it) {
        int l = it * 256 + tid;
        int r = l >> 5, cc = (l & 31) << 3;
        *(uint4*)&As[r][cc] = *(const uint4*)&attnb[(size_t)(mbase + r) * C_ + cc];
    }
    __syncthreads();
#pragma unroll
    for (int mt = 0; mt < 4; ++mt) {
        f32x4_t acc = {0.f, 0.f, 0.f, 0.f};
#pragma unroll
        for (int ks = 0; ks < 8; ++ks) {
            bf16x8_t a = *(const bf16x8_t*)&As[mt * 16 + l16][ks * 32 + quad * 8];
            acc = __builtin_amdgcn_mfma_f32_16x16x32_bf16(a, breg[ks], acc, 0, 0, 0);
        }
        const int row0 = mbase + mt * 16 + quad * 4;
#pragma unroll
        for (int r = 0; r < 4; ++r)
            out[(size_t)(row0 + r) * C_ + colz + l16] = acc[r] + bcol;
    }
}

// ---------------- launch ----------------

extern "C" void kernel_launch(void* const* d_in, const int* in_sizes, int n_in,
                              void* d_out, int out_size, void* d_ws, size_t ws_size,
                              hipStream_t stream) {
    const float* x  = (const float*)d_in[0];
    const int* q_id = (const int*)d_in[1];
    const int* k_id = (const int*)d_in[2];
    const float* Wq = (const float*)d_in[3];
    const float* bq = (const float*)d_in[4];
    const float* Wk = (const float*)d_in[5];
    const float* bk = (const float*)d_in[6];
    const float* Wv = (const float*)d_in[7];
    const float* bv = (const float*)d_in[8];
    const float* Wx = (const float*)d_in[9];
    const float* bx = (const float*)d_in[10];
    float* out = (float*)d_out;

    char* ws = (char*)d_ws;
    unsigned short* qb    = (unsigned short*)ws;   ws += (size_t)MR * C_ * 2;
    unsigned short* kvb   = (unsigned short*)ws;   ws += (size_t)MR * 512 * 2;
    unsigned short* attnb = (unsigned short*)ws;   ws += (size_t)MR * C_ * 2;
    int* count = (int*)ws;                         ws += 2 * S_ * 4;
    int* done  = (int*)ws;                         ws += 16 * 4;
    int* base  = (int*)ws;                         ws += (2 * S_ + 1) * 4;
    int* cursor = (int*)ws;                        ws += 2 * S_ * 4;
    int* koff_sorted = (int*)ws;

    hipMemsetAsync(count, 0, (2 * S_ + 16) * sizeof(int), stream);   // count + done
    prep_kernel<<<PREP_BLOCKS, 256, 0, stream>>>(q_id, k_id, count, done, base, cursor);
    scatter_qkv_kernel<<<1024, 256, 0, stream>>>(x, q_id, k_id, cursor, koff_sorted,
                                                 Wq, Wk, Wv, bq, bk, bv, qb, kvb);
    attn_edge<<<S_ / 2, 256, 0, stream>>>(qb, kvb, base, koff_sorted, attnb);
    gemm_proj<<<512, 256, 0, stream>>>(attnb, Wx, bx, out);
}

// Round 10
// 141.666 us; speedup vs baseline: 1.1642x; 1.0413x over previous
//
#include <hip/hip_runtime.h>

// Problem constants (fixed by the dataset)
constexpr int S_  = 4096;
constexpr int B_  = 2;
constexpr int C_  = 256;
constexpr int H_  = 8;
constexpr int E_  = 131072;
constexpr int MR  = S_ * B_;   // 8192 rows for all GEMMs
constexpr int PREP_BLOCKS = 640;   // 512 hist + 128 W-cast

typedef __attribute__((ext_vector_type(8))) short bf16x8_t;
typedef __attribute__((ext_vector_type(4))) float f32x4_t;

__device__ __forceinline__ unsigned short f2bf(float f) {
    unsigned int u = __float_as_uint(f);
    u += 0x7fffu + ((u >> 16) & 1u);   // round-to-nearest-even
    return (unsigned short)(u >> 16);
}
__device__ __forceinline__ float bflo(unsigned int u) { return __uint_as_float(u << 16); }
__device__ __forceinline__ float bfhi(unsigned int u) { return __uint_as_float(u & 0xffff0000u); }

__device__ __forceinline__ void cast8(const float* __restrict__ src, unsigned short* __restrict__ dst, int i) {
    const float4* s = (const float4*)src + (size_t)i * 2;
    float4 a = s[0], b = s[1];
    uint4 o;
    o.x = (unsigned)f2bf(a.x) | ((unsigned)f2bf(a.y) << 16);
    o.y = (unsigned)f2bf(a.z) | ((unsigned)f2bf(a.w) << 16);
    o.z = (unsigned)f2bf(b.x) | ((unsigned)f2bf(b.y) << 16);
    o.w = (unsigned)f2bf(b.z) | ((unsigned)f2bf(b.w) << 16);
    *((uint4*)dst + i) = o;
}

// 4-lane butterfly sum via DPP quad_perm (VALU, no LDS round-trip like __shfl_xor)
__device__ __forceinline__ float quad_sum(float p) {
    p += __uint_as_float((unsigned)__builtin_amdgcn_update_dpp(
            0, (int)__float_as_uint(p), 0xB1 /*quad_perm [1,0,3,2]*/, 0xF, 0xF, true));
    p += __uint_as_float((unsigned)__builtin_amdgcn_update_dpp(
            0, (int)__float_as_uint(p), 0x4E /*quad_perm [2,3,0,1]*/, 0xF, 0xF, true));
    return p;
}

// ---------------- K1: bucketed histogram + W casts; last block does the scan ----------------
// count/base/cursor have 2S entries: bucket A (k<2048) in [0,S), bucket B in [S,2S).

__global__ __launch_bounds__(256) void prep_kernel(
        const int* __restrict__ q_id, const int* __restrict__ k_id,
        const float* __restrict__ Wq, const float* __restrict__ Wk,
        const float* __restrict__ Wv, const float* __restrict__ Wx,
        unsigned short* __restrict__ Wb,
        int* __restrict__ count, int* done,
        int* __restrict__ base, int* __restrict__ cursor) {
    const int bid = blockIdx.x, tid = threadIdx.x;
    if (bid < 512) {
        int e = bid * 256 + tid;
        int q = q_id[e], k = k_id[e];
        atomicAdd(&count[q + ((k >> 11) << 12)], 1);   // bucket = (k>=2048)
    } else {
        int idx = bid - 512;
        int z = idx >> 5;
        const float* src = (z == 0) ? Wq : (z == 1) ? Wk : (z == 2) ? Wv : Wx;
        cast8(src, Wb + (size_t)z * (C_ * C_), (idx & 31) * 256 + tid);
    }

    // ---- last-arriving block performs the 8192-entry exclusive scan ----
    __shared__ int amLast;
    __syncthreads();   // my atomics/stores complete before the done-add
    if (tid == 0) {
        int d = __hip_atomic_fetch_add(done, 1, __ATOMIC_RELAXED, __HIP_MEMORY_SCOPE_AGENT);
        amLast = (d == PREP_BLOCKS - 1);
    }
    __syncthreads();
    if (!amLast) return;
    __builtin_amdgcn_fence(__ATOMIC_ACQUIRE, "agent");   // invalidate caches before reading count

    const int lane = tid & 63, w = tid >> 6;
    const int4* cp = (const int4*)count;
    int4 c[8];
#pragma unroll
    for (int j = 0; j < 8; ++j) c[j] = cp[tid * 8 + j];
    int tsum = 0;
#pragma unroll
    for (int j = 0; j < 8; ++j) tsum += c[j].x + c[j].y + c[j].z + c[j].w;
    int incl = tsum;
#pragma unroll
    for (int off = 1; off < 64; off <<= 1) {
        int y = __shfl_up(incl, off);
        if (lane >= off) incl += y;
    }
    __shared__ int wsums[4];
    if (lane == 63) wsums[w] = incl;
    __syncthreads();
    int ws0 = wsums[0], ws1 = wsums[1], ws2 = wsums[2];
    if (tid == 0) base[2 * S_] = E_;
    int woff = (w > 0 ? ws0 : 0) + (w > 1 ? ws1 : 0) + (w > 2 ? ws2 : 0);
    int run = woff + incl - tsum;
    int idx = tid * 32;
#define EMIT(V) { base[idx] = run; cursor[idx] = run; run += (V); ++idx; }
#pragma unroll
    for (int j = 0; j < 8; ++j) {
        EMIT(c[j].x) EMIT(c[j].y) EMIT(c[j].z) EMIT(c[j].w)
    }
#undef EMIT
}

// ---------------- K2: scatter + QKV GEMM (A cast fp32->bf16 during staging) ----------------

__global__ __launch_bounds__(256) void scatter_qkv_kernel(
        const float* __restrict__ x,
        const int* __restrict__ q_id, const int* __restrict__ k_id,
        int* __restrict__ cursor, int* __restrict__ koff,
        const unsigned short* __restrict__ Wb,
        const float* __restrict__ bq, const float* __restrict__ bk, const float* __restrict__ bv,
        unsigned short* __restrict__ qb, unsigned short* __restrict__ kvb) {
    __shared__ __align__(16) unsigned short As[64][264];   // 33.8 KB, +8 pad
    const int bid = blockIdx.x, tid = threadIdx.x;
    if (bid >= 512) {
        int e = (bid - 512) * 256 + tid;
        int q = q_id[e], k = k_id[e];
        int pos = atomicAdd(&cursor[q + ((k >> 11) << 12)], 1);
        koff[pos] = k << 10;               // element offset of row-pair in kvb
        return;
    }
    const int nb = bid & 3, mg = bid >> 2;
    const int lane = tid & 63, wave = tid >> 6;
    const int l16 = lane & 15, quad = lane >> 4;
    const int colz = (nb << 6) + (wave << 4);

    // Three B-strips: rows [colz, colz+16) of Wq, Wk, Wv
    bf16x8_t breg[3][8];
#pragma unroll
    for (int z = 0; z < 3; ++z) {
        const unsigned short* Wrow = Wb + (size_t)z * (C_ * C_) + (size_t)(colz + l16) * C_;
#pragma unroll
        for (int ks = 0; ks < 8; ++ks)
            breg[z][ks] = *(const bf16x8_t*)(Wrow + ks * 32 + quad * 8);
    }
    const float bc0 = bq[colz + l16];
    const float bc1 = bk[colz + l16];
    const float bc2 = bv[colz + l16];

    const int mbase = mg * 64;
    // stage A: 64 rows x 256 cols, fp32 -> bf16 into LDS
#pragma unroll
    for (int it = 0; it < 8; ++it) {
        int u = it * 256 + tid;
        int r = u >> 5, cc = (u & 31) << 3;
        const float4* s = (const float4*)(x + (size_t)(mbase + r) * C_ + cc);
        float4 a = s[0], b = s[1];
        uint4 o;
        o.x = (unsigned)f2bf(a.x) | ((unsigned)f2bf(a.y) << 16);
        o.y = (unsigned)f2bf(a.z) | ((unsigned)f2bf(a.w) << 16);
        o.z = (unsigned)f2bf(b.x) | ((unsigned)f2bf(b.y) << 16);
        o.w = (unsigned)f2bf(b.z) | ((unsigned)f2bf(b.w) << 16);
        *(uint4*)&As[r][cc] = o;
    }
    __syncthreads();

#pragma unroll
    for (int mt = 0; mt < 4; ++mt) {
        bf16x8_t a[8];
#pragma unroll
        for (int ks = 0; ks < 8; ++ks)
            a[ks] = *(const bf16x8_t*)&As[mt * 16 + l16][ks * 32 + quad * 8];
        const int row0 = mbase + mt * 16 + quad * 4;
        {   // q
            f32x4_t acc = {0.f, 0.f, 0.f, 0.f};
#pragma unroll
            for (int ks = 0; ks < 8; ++ks)
                acc = __builtin_amdgcn_mfma_f32_16x16x32_bf16(a[ks], breg[0][ks], acc, 0, 0, 0);
#pragma unroll
            for (int r = 0; r < 4; ++r)
                qb[(size_t)(row0 + r) * 256 + colz + l16] = f2bf(acc[r] + bc0);
        }
        {   // k  (kvb cols [0,256))
            f32x4_t acc = {0.f, 0.f, 0.f, 0.f};
#pragma unroll
            for (int ks = 0; ks < 8; ++ks)
                acc = __builtin_amdgcn_mfma_f32_16x16x32_bf16(a[ks], breg[1][ks], acc, 0, 0, 0);
#pragma unroll
            for (int r = 0; r < 4; ++r)
                kvb[(size_t)(row0 + r) * 512 + colz + l16] = f2bf(acc[r] + bc1);
        }
        {   // v  (kvb cols [256,512))
            f32x4_t acc = {0.f, 0.f, 0.f, 0.f};
#pragma unroll
            for (int ks = 0; ks < 8; ++ks)
                acc = __builtin_amdgcn_mfma_f32_16x16x32_bf16(a[ks], breg[2][ks], acc, 0, 0, 0);
#pragma unroll
            for (int r = 0; r < 4; ++r)
                kvb[(size_t)(row0 + r) * 512 + 256 + colz + l16] = f2bf(acc[r] + bc2);
        }
    }
}

// ---------------- K3: edge attention, 2-bucket, 4-deep pipeline, DPP reduce ----------------

__global__ __launch_bounds__(256) void attn_edge(
        const unsigned short* __restrict__ qb, const unsigned short* __restrict__ kvb,
        const int* __restrict__ base, const int* __restrict__ koff,
        unsigned short* __restrict__ attnb) {
    __shared__ float red[2][64][9];
    const int lane = threadIdx.x & 63;
    const int wave = threadIdx.x >> 6;
    const int rw = wave >> 1, part = wave & 1;
    const int s = blockIdx.x * 2 + rw;
    const int half = lane >> 5, hl = lane & 31;

    const uint4 qq = *((const uint4*)(qb + (size_t)(s * 2 + half) * C_) + hl);
    const float q0 = bflo(qq.x), q1 = bfhi(qq.x), q2 = bflo(qq.y), q3 = bfhi(qq.y);
    const float q4 = bflo(qq.z), q5 = bfhi(qq.z), q6 = bflo(qq.w), q7 = bfhi(qq.w);

    float a0 = 0.f, a1 = 0.f, a2 = 0.f, a3 = 0.f, a4 = 0.f, a5 = 0.f, a6 = 0.f, a7 = 0.f;
    float wsum = 0.f;
    // 1/sqrt(32) * log2(e): fold softmax scale into exp2 argument
    const float scale2 = 0.25503509f;

    auto edge = [&](const uint4& kk, const uint4& vv) {
        float p = q0 * bflo(kk.x) + q1 * bfhi(kk.x)
                + q2 * bflo(kk.y) + q3 * bfhi(kk.y)
                + q4 * bflo(kk.z) + q5 * bfhi(kk.z)
                + q6 * bflo(kk.w) + q7 * bfhi(kk.w);
        p = quad_sum(p);                       // 4-lane butterfly via DPP (VALU)
        const float w = exp2f(p * scale2);
        a0 = fmaf(w, bflo(vv.x), a0); a1 = fmaf(w, bfhi(vv.x), a1);
        a2 = fmaf(w, bflo(vv.y), a2); a3 = fmaf(w, bfhi(vv.y), a3);
        a4 = fmaf(w, bflo(vv.z), a4); a5 = fmaf(w, bfhi(vv.z), a5);
        a6 = fmaf(w, bflo(vv.w), a6); a7 = fmaf(w, bfhi(vv.w), a7);
        wsum += w;
    };
    auto fetch = [&](int my, int t, uint4& kk, uint4& vv) {
        int o = __builtin_amdgcn_readlane(my, part + 2 * t);
        const uint4* p = (const uint4*)(kvb + o + half * 512);
        kk = p[hl]; vv = p[32 + hl];
    };

    // two k-buckets; each has a ~4 MB kvb working set (XCD L2-resident).
#pragma unroll
    for (int seg = 0; seg < 2; ++seg) {
        const int cb = seg * S_ + s;
        const int e0 = __builtin_amdgcn_readfirstlane(base[cb]);
        const int e1 = __builtin_amdgcn_readfirstlane(base[cb + 1]);
        for (int b0 = e0; b0 < e1; b0 += 64) {
            const int m = min(64, e1 - b0);
            const int my = koff[b0 + ((lane < m) ? lane : 0)];
            const int nm = (m > part) ? ((m - part + 1) >> 1) : 0;
            uint4 k0 = {}, v0 = {}, k1 = {}, v1 = {};
            uint4 k2 = {}, v2 = {}, k3 = {}, v3 = {};
            if (nm > 0) fetch(my, 0, k0, v0);
            if (nm > 1) fetch(my, 1, k1, v1);
            if (nm > 2) fetch(my, 2, k2, v2);
            if (nm > 3) fetch(my, 3, k3, v3);
            int t = 0;
            for (; t + 7 < nm; t += 4) {
                edge(k0, v0); fetch(my, t + 4, k0, v0);
                edge(k1, v1); fetch(my, t + 5, k1, v1);
                edge(k2, v2); fetch(my, t + 6, k2, v2);
                edge(k3, v3); fetch(my, t + 7, k3, v3);
            }
            const int rem = nm - t;   // 0..7
            if (rem > 0) { edge(k0, v0); if (rem > 4) fetch(my, t + 4, k0, v0); }
            if (rem > 1) { edge(k1, v1); if (rem > 5) fetch(my, t + 5, k1, v1); }
            if (rem > 2) { edge(k2, v2); if (rem > 6) fetch(my, t + 6, k2, v2); }
            if (rem > 3) edge(k3, v3);
            if (rem > 4) edge(k0, v0);
            if (rem > 5) edge(k1, v1);
            if (rem > 6) edge(k2, v2);
        }
    }

    if (part == 1) {
        float* r = red[rw][lane];
        r[0] = a0; r[1] = a1; r[2] = a2; r[3] = a3;
        r[4] = a4; r[5] = a5; r[6] = a6; r[7] = a7; r[8] = wsum;
    }
    __syncthreads();
    if (part == 0) {
        const float* r = red[rw][lane];
        a0 += r[0]; a1 += r[1]; a2 += r[2]; a3 += r[3];
        a4 += r[4]; a5 += r[5]; a6 += r[6]; a7 += r[7]; wsum += r[8];
        const float inv = 1.0f / wsum;
        uint4 o;
        o.x = (unsigned)f2bf(a0 * inv) | ((unsigned)f2bf(a1 * inv) << 16);
        o.y = (unsigned)f2bf(a2 * inv) | ((unsigned)f2bf(a3 * inv) << 16);
        o.z = (unsigned)f2bf(a4 * inv) | ((unsigned)f2bf(a5 * inv) << 16);
        o.w = (unsigned)f2bf(a6 * inv) | ((unsigned)f2bf(a7 * inv) << 16);
        *((uint4*)(attnb + (size_t)(s * 2 + half) * C_) + hl) = o;
    }
}

// ---------------- K4: output projection (weights-in-registers) ----------------

__global__ __launch_bounds__(256) void gemm_proj(
        const unsigned short* __restrict__ attnb, const unsigned short* __restrict__ Wxb,
        const float* __restrict__ bx, float* __restrict__ out) {
    __shared__ __align__(16) unsigned short As[64][264];
    const int tid = threadIdx.x;
    const int nb = blockIdx.x & 3, mg = blockIdx.x >> 2;
    const int lane = tid & 63, wave = tid >> 6;
    const int l16 = lane & 15, quad = lane >> 4;
    const int colz = (nb << 6) + (wave << 4);

    const unsigned short* Wrow = Wxb + (size_t)(colz + l16) * C_;
    bf16x8_t breg[8];
#pragma unroll
    for (int ks = 0; ks < 8; ++ks)
        breg[ks] = *(const bf16x8_t*)(Wrow + ks * 32 + quad * 8);
    const float bcol = bx[colz + l16];

    const int mbase = mg * 64;
#pragma unroll
    for (int it = 0; it < 8; ++it) {
        int l = it * 256 + tid;
        int r = l >> 5, cc = (l & 31) << 3;
        *(uint4*)&As[r][cc] = *(const uint4*)&attnb[(size_t)(mbase + r) * C_ + cc];
    }
    __syncthreads();
#pragma unroll
    for (int mt = 0; mt < 4; ++mt) {
        f32x4_t acc = {0.f, 0.f, 0.f, 0.f};
#pragma unroll
        for (int ks = 0; ks < 8; ++ks) {
            bf16x8_t a = *(const bf16x8_t*)&As[mt * 16 + l16][ks * 32 + quad * 8];
            acc = __builtin_amdgcn_mfma_f32_16x16x32_bf16(a, breg[ks], acc, 0, 0, 0);
        }
        const int row0 = mbase + mt * 16 + quad * 4;
#pragma unroll
        for (int r = 0; r < 4; ++r)
            out[(size_t)(row0 + r) * C_ + colz + l16] = acc[r] + bcol;
    }
}

// ---------------- launch ----------------

extern "C" void kernel_launch(void* const* d_in, const int* in_sizes, int n_in,
                              void* d_out, int out_size, void* d_ws, size_t ws_size,
                              hipStream_t stream) {
    const float* x  = (const float*)d_in[0];
    const int* q_id = (const int*)d_in[1];
    const int* k_id = (const int*)d_in[2];
    const float* Wq = (const float*)d_in[3];
    const float* bq = (const float*)d_in[4];
    const float* Wk = (const float*)d_in[5];
    const float* bk = (const float*)d_in[6];
    const float* Wv = (const float*)d_in[7];
    const float* bv = (const float*)d_in[8];
    const float* Wx = (const float*)d_in[9];
    const float* bx = (const float*)d_in[10];
    float* out = (float*)d_out;

    char* ws = (char*)d_ws;
    unsigned short* qb    = (unsigned short*)ws;   ws += (size_t)MR * C_ * 2;
    unsigned short* kvb   = (unsigned short*)ws;   ws += (size_t)MR * 512 * 2;
    unsigned short* attnb = (unsigned short*)ws;   ws += (size_t)MR * C_ * 2;
    unsigned short* Wb    = (unsigned short*)ws;   ws += (size_t)4 * C_ * C_ * 2;
    int* count = (int*)ws;                         ws += 2 * S_ * 4;
    int* done  = (int*)ws;                         ws += 16 * 4;
    int* base  = (int*)ws;                         ws += (2 * S_ + 1) * 4;
    int* cursor = (int*)ws;                        ws += 2 * S_ * 4;
    int* koff_sorted = (int*)ws;

    hipMemsetAsync(count, 0, (2 * S_ + 16) * sizeof(int), stream);   // count + done
    prep_kernel<<<PREP_BLOCKS, 256, 0, stream>>>(q_id, k_id, Wq, Wk, Wv, Wx, Wb,
                                                 count, done, base, cursor);
    scatter_qkv_kernel<<<1024, 256, 0, stream>>>(x, q_id, k_id, cursor, koff_sorted,
                                                 Wb, bq, bk, bv, qb, kvb);
    attn_edge<<<S_ / 2, 256, 0, stream>>>(qb, kvb, base, koff_sorted, attnb);
    gemm_proj<<<512, 256, 0, stream>>>(attnb, Wb + (size_t)3 * C_ * C_, bx, out);
}